// Round 7
// baseline (447.441 us; speedup 1.0000x reference)
//
#include <hip/hip_runtime.h>
#include <math.h>

#define B_    2
#define S_    2048
#define E_    2048
#define H_    32
#define HKV_  8
#define D_    64

typedef __bf16 bf16x8 __attribute__((ext_vector_type(8)));
typedef float  f32x4  __attribute__((ext_vector_type(4)));
typedef float  f32x16 __attribute__((ext_vector_type(16)));
typedef unsigned int u32x2 __attribute__((ext_vector_type(2)));
typedef unsigned int u32x4 __attribute__((ext_vector_type(4)));

#define GPTR(x) ((const __attribute__((address_space(1))) void*)(x))
#define LPTR(x) ((__attribute__((address_space(3))) void*)(x))

// 0.125 * log2(e): folded into Q so attention softmax is exp2-direct.
#define QK_SCALE_LOG2E 0.18033688011112042f

// ---------------------------------------------------------------------------
// fp32 -> bf16 flat convert (x)
// ---------------------------------------------------------------------------
__global__ __launch_bounds__(256) void convert_kernel(
    const float* __restrict__ in, __bf16* __restrict__ out, int n8)
{
    const int i = blockIdx.x * 256 + threadIdx.x;
    if (i >= n8) return;
    const float4 a = ((const float4*)in)[i * 2];
    const float4 b = ((const float4*)in)[i * 2 + 1];
    bf16x8 o;
    o[0] = (__bf16)a.x; o[1] = (__bf16)a.y; o[2] = (__bf16)a.z; o[3] = (__bf16)a.w;
    o[4] = (__bf16)b.x; o[5] = (__bf16)b.y; o[6] = (__bf16)b.z; o[7] = (__bf16)b.w;
    ((bf16x8*)out)[i] = o;
}

// ---------------------------------------------------------------------------
// All 4 weight transposes (fp32 (K,N) -> bf16 (N,K)) in ONE dispatch.
// ---------------------------------------------------------------------------
__global__ __launch_bounds__(256) void transpose_convert_all_kernel(
    const float* __restrict__ wq, const float* __restrict__ wk,
    const float* __restrict__ wv, const float* __restrict__ wo,
    __bf16* __restrict__ wT, __bf16* __restrict__ woT)
{
    const float* in; __bf16* out; int N, xb;
    const int x = blockIdx.x;
    if (x < 64)      { in = wq; out = wT;                        N = 2048; xb = x; }
    else if (x < 80) { in = wk; out = wT + (size_t)2048 * 2048;  N = 512;  xb = x - 64; }
    else if (x < 96) { in = wv; out = wT + (size_t)2560 * 2048;  N = 512;  xb = x - 80; }
    else             { in = wo; out = woT;                       N = 2048; xb = x - 96; }
    const int K = 2048;

    __shared__ float tile[32][33];
    const int k0 = blockIdx.y * 32, n0 = xb * 32;
    const int r  = threadIdx.x >> 3;
    const int c4 = (threadIdx.x & 7) * 4;
    const float4 v = *(const float4*)&in[(size_t)(k0 + r) * N + n0 + c4];
    tile[r][c4 + 0] = v.x; tile[r][c4 + 1] = v.y;
    tile[r][c4 + 2] = v.z; tile[r][c4 + 3] = v.w;
    __syncthreads();
    ushort4 o;
    __bf16 h0 = (__bf16)tile[c4 + 0][r]; o.x = __builtin_bit_cast(unsigned short, h0);
    __bf16 h1 = (__bf16)tile[c4 + 1][r]; o.y = __builtin_bit_cast(unsigned short, h1);
    __bf16 h2 = (__bf16)tile[c4 + 2][r]; o.z = __builtin_bit_cast(unsigned short, h2);
    __bf16 h3 = (__bf16)tile[c4 + 3][r]; o.w = __builtin_bit_cast(unsigned short, h3);
    *(ushort4*)&out[(size_t)(n0 + r) * K + k0 + c4] = o;
}

// ---------------------------------------------------------------------------
// Pipelined GEMM (unchanged from R5: 4-slot ring, counted vmcnt).
// ---------------------------------------------------------------------------
template<int BN> struct PG {
    static constexpr int BM     = 256;
    static constexpr int BK     = 32;
    static constexpr int ASLOT  = BM * BK;
    static constexpr int BSLOT  = BN * BK;
    static constexpr int SLOT   = ASLOT + BSLOT;
    static constexpr int BINSTR = BN / 128;
    static constexpr int L      = 2 + BINSTR;
    static constexpr int NJ     = BN / 64;
};

template<int BN>
__device__ __forceinline__ void stage_tile(
    const __bf16* __restrict__ A, const __bf16* __restrict__ Bt,
    int m0, int n0, int K, int T, __bf16* sl, int t, int wbase)
{
    using G = PG<BN>;
    const int k0   = T * G::BK;
    const int rsub = t >> 2;
    const int cp   = t & 3;
#pragma unroll
    for (int g = 0; g < 2; ++g) {
        const int row = g * 128 + rsub;
        const int cl  = cp ^ ((row >> 1) & 3);
        __builtin_amdgcn_global_load_lds(
            GPTR(A + (size_t)(m0 + row) * K + k0 + cl * 8),
            LPTR(sl + (g * 512 + wbase) * 8), 16, 0, 0);
    }
#pragma unroll
    for (int g = 0; g < G::BINSTR; ++g) {
        const int row = g * 128 + rsub;
        const int cl  = cp ^ ((row >> 1) & 3);
        __builtin_amdgcn_global_load_lds(
            GPTR(Bt + (size_t)(n0 + row) * K + k0 + cl * 8),
            LPTR(sl + G::ASLOT + (g * 512 + wbase) * 8), 16, 0, 0);
    }
}

template<int BN>
__device__ __forceinline__ void compute_tile(
    const __bf16* sl, int wrow, int wcol, int col, int quad,
    f32x4 acc[8][PG<BN>::NJ])
{
    using G = PG<BN>;
    bf16x8 af[8], bfr[G::NJ];
#pragma unroll
    for (int i = 0; i < 8; ++i) {
        const int m = wrow + i * 16 + col;
        af[i] = *(const bf16x8*)&sl[m * 32 + ((quad ^ ((m >> 1) & 3)) * 8)];
    }
#pragma unroll
    for (int j = 0; j < G::NJ; ++j) {
        const int n = wcol + j * 16 + col;
        bfr[j] = *(const bf16x8*)&sl[G::ASLOT + n * 32 + ((quad ^ ((n >> 1) & 3)) * 8)];
    }
    __builtin_amdgcn_s_setprio(1);
#pragma unroll
    for (int i = 0; i < 8; ++i)
#pragma unroll
        for (int j = 0; j < G::NJ; ++j)
            acc[i][j] = __builtin_amdgcn_mfma_f32_16x16x32_bf16(
                af[i], bfr[j], acc[i][j], 0, 0, 0);
    __builtin_amdgcn_s_setprio(0);
}

template<int BN>
__device__ __forceinline__ void gemm_pipe_body(
    const __bf16* __restrict__ A, const __bf16* __restrict__ Bt,
    int m0, int n0, int K, __bf16* sL, f32x4 acc[8][PG<BN>::NJ])
{
    using G = PG<BN>;
    const int t     = threadIdx.x;
    const int wbase = t & ~63;
    const int lane  = t & 63;
    const int col   = lane & 15;
    const int quad  = lane >> 4;
    const int w     = t >> 6;
    const int wrow  = (w >> 2) * 128;
    const int wcol  = (w & 3) * (BN / 4);
    const int NT    = K / G::BK;

    stage_tile<BN>(A, Bt, m0, n0, K, 0, sL + 0 * G::SLOT, t, wbase);
    stage_tile<BN>(A, Bt, m0, n0, K, 1, sL + 1 * G::SLOT, t, wbase);
    stage_tile<BN>(A, Bt, m0, n0, K, 2, sL + 2 * G::SLOT, t, wbase);

    int T = 0;
#pragma unroll 1
    for (; T < NT - 3; ++T) {
        asm volatile("s_waitcnt vmcnt(%0)" :: "n"(2 * G::L) : "memory");
        __builtin_amdgcn_s_barrier();
        stage_tile<BN>(A, Bt, m0, n0, K, T + 3, sL + ((T + 3) & 3) * G::SLOT, t, wbase);
        compute_tile<BN>(sL + (T & 3) * G::SLOT, wrow, wcol, col, quad, acc);
    }
    asm volatile("s_waitcnt vmcnt(%0)" :: "n"(2 * G::L) : "memory");
    __builtin_amdgcn_s_barrier();
    compute_tile<BN>(sL + (T & 3) * G::SLOT, wrow, wcol, col, quad, acc); ++T;
    asm volatile("s_waitcnt vmcnt(%0)" :: "n"(G::L) : "memory");
    __builtin_amdgcn_s_barrier();
    compute_tile<BN>(sL + (T & 3) * G::SLOT, wrow, wcol, col, quad, acc); ++T;
    asm volatile("s_waitcnt vmcnt(0)" ::: "memory");
    __builtin_amdgcn_s_barrier();
    compute_tile<BN>(sL + (T & 3) * G::SLOT, wrow, wcol, col, quad, acc);
}

// ---------------------------------------------------------------------------
// QKV GEMM (BM=256, BN=256): 192 blocks, fused RoPE/scale epilogue.
// ---------------------------------------------------------------------------
__global__ __launch_bounds__(512, 2) void gemm_qkv_kernel(
    const __bf16* __restrict__ xb, const __bf16* __restrict__ wT,
    const float* __restrict__ fc, const float* __restrict__ fs,
    __bf16* __restrict__ qb, __bf16* __restrict__ kb, __bf16* __restrict__ vb)
{
    __shared__ __bf16 sL[4 * PG<256>::SLOT];   // 128 KiB
    f32x4 acc[8][4];
#pragma unroll
    for (int i = 0; i < 8; ++i)
#pragma unroll
        for (int j = 0; j < 4; ++j) acc[i][j] = (f32x4){0.f, 0.f, 0.f, 0.f};

    const int lin     = blockIdx.x;
    const int logical = (lin & 7) * 24 + (lin >> 3);
    const int bx      = logical % 12;
    const int m0      = (logical / 12) * 256;
    const int n0      = bx * 256;

    gemm_pipe_body<256>(xb, wT, m0, n0, E_, sL, acc);

    __bf16* Cp; int ldc, base;
    if (bx < 8)       { Cp = qb; ldc = H_ * D_;   base = 0;    }
    else if (bx < 10) { Cp = kb; ldc = HKV_ * D_; base = 2048; }
    else              { Cp = vb; ldc = HKV_ * D_; base = 2560; }
    const bool  doRope = (bx < 10);
    const float qsc    = (bx < 8) ? QK_SCALE_LOG2E : 1.0f;

    const int t    = threadIdx.x;
    const int lane = t & 63;
    const int col  = lane & 15;
    const int quad = lane >> 4;
    const int w    = t >> 6;
    const int wrow = (w >> 2) * 128;
    const int wcol = (w & 3) * 64;
#pragma unroll
    for (int i = 0; i < 8; ++i)
#pragma unroll
        for (int j = 0; j < 4; ++j)
#pragma unroll
            for (int r = 0; r < 4; ++r) {
                const int m  = m0 + wrow + i * 16 + quad * 4 + r;
                const int ng = n0 + wcol + j * 16 + col;
                float val = acc[i][j][r] * qsc;
                if (doRope) {
                    const int   s    = m & (S_ - 1);
                    const int   pair = (ng & 63) >> 1;
                    const float c    = fc[s * 32 + pair];
                    const float sn   = fs[s * 32 + pair];
                    const float oth  = __shfl_xor(val, 1);
                    val = (lane & 1) ? (oth * sn + val * c)
                                     : (val * c - oth * sn);
                }
                Cp[(size_t)m * ldc + (ng - base)] = (__bf16)val;
            }
}

// ---------------------------------------------------------------------------
// Output GEMM (BM=256, BN=128): 256 blocks, bias epilogue.
// ---------------------------------------------------------------------------
__global__ __launch_bounds__(512, 2) void gemm_out_kernel(
    const __bf16* __restrict__ ob, const __bf16* __restrict__ woT,
    const float* __restrict__ bias, float* __restrict__ out)
{
    __shared__ __bf16 sL[4 * PG<128>::SLOT];   // 96 KiB
    f32x4 acc[8][2];
#pragma unroll
    for (int i = 0; i < 8; ++i)
#pragma unroll
        for (int j = 0; j < 2; ++j) acc[i][j] = (f32x4){0.f, 0.f, 0.f, 0.f};

    const int lin     = blockIdx.x;
    const int logical = (lin & 7) * 32 + (lin >> 3);
    const int n0      = (logical % 16) * 128;
    const int m0      = (logical / 16) * 256;

    gemm_pipe_body<128>(ob, woT, m0, n0, H_ * D_, sL, acc);

    const int t    = threadIdx.x;
    const int lane = t & 63;
    const int col  = lane & 15;
    const int quad = lane >> 4;
    const int w    = t >> 6;
    const int wrow = (w >> 2) * 128;
    const int wcol = (w & 3) * 32;
#pragma unroll
    for (int i = 0; i < 8; ++i)
#pragma unroll
        for (int j = 0; j < 2; ++j)
#pragma unroll
            for (int r = 0; r < 4; ++r) {
                const int m = m0 + wrow + i * 16 + quad * 4 + r;
                const int n = n0 + wcol + j * 16 + col;
                out[(size_t)m * E_ + n] = acc[i][j][r] + bias[n];
            }
}

// ---------------------------------------------------------------------------
// MFMA flash attention v5: 64 q-rows per WAVE (256 q per block).
// R6 analysis: all 4 waves of a block read IDENTICAL aK/vbf LDS fragments
// (they differ only in q, held in registers) -> LDS traffic ~2.1 GB total,
// the largest pipe cost (~30-40 µs), scaling with waves not work. Fix:
// each wave now runs TWO q-sets (qs=0,1) through ONE aK+vbf read per tile
// -> per-q LDS traffic halves, and the two q-set chains double per-wave ILP.
// Register schedule (peak ~230, fits (256,2) without spill):
//   aK read -> QK(qs0) -> vbf read (hides under sm0) -> sm0/pack0 ->
//   PV(qs0) -> QK(qs1, aK dies) -> sm1/pack1 -> PV(qs1, vbf dies).
// Spill tripwire: WRITE_SIZE must stay 16384 (R3: forced-occupancy spill
// was 287 MB and 2x slower).
// ---------------------------------------------------------------------------
struct StageRegs {
    bf16x8  k0, k1;
    ushort4 va0, vc0, va1, vc1;
};

__device__ __forceinline__ void stage_load(
    StageRegs& r, const __bf16* kbase, const __bf16* vbase, int j0,
    int kkey, int kd, int vkp, int vdg)
{
    const int KSTR = HKV_ * D_;   // 512
    const __bf16* kr = kbase + (size_t)(j0 + kkey) * KSTR + kd;
    r.k0 = ((const bf16x8*)kr)[0];
    r.k1 = ((const bf16x8*)kr)[1];
    const __bf16* v0 = vbase + (size_t)(j0 + vkp) * KSTR + vdg;
    r.va0 = *(const ushort4*)(v0);
    r.vc0 = *(const ushort4*)(v0 + KSTR);
    r.va1 = *(const ushort4*)(v0 + 32);
    r.vc1 = *(const ushort4*)(v0 + KSTR + 32);
}

__device__ __forceinline__ void stage_write(
    const StageRegs& r, __bf16 (*sK)[72], __bf16 (*sVT)[72],
    int kkey, int kd, int vkp, int vdg)
{
    *(bf16x8*)&sK[kkey][kd]     = r.k0;
    *(bf16x8*)&sK[kkey][kd + 8] = r.k1;
    *(unsigned int*)&sVT[vdg + 0][vkp]      = ((unsigned)r.vc0.x << 16) | r.va0.x;
    *(unsigned int*)&sVT[vdg + 1][vkp]      = ((unsigned)r.vc0.y << 16) | r.va0.y;
    *(unsigned int*)&sVT[vdg + 2][vkp]      = ((unsigned)r.vc0.z << 16) | r.va0.z;
    *(unsigned int*)&sVT[vdg + 3][vkp]      = ((unsigned)r.vc0.w << 16) | r.va0.w;
    *(unsigned int*)&sVT[vdg + 32 + 0][vkp] = ((unsigned)r.vc1.x << 16) | r.va1.x;
    *(unsigned int*)&sVT[vdg + 32 + 1][vkp] = ((unsigned)r.vc1.y << 16) | r.va1.y;
    *(unsigned int*)&sVT[vdg + 32 + 2][vkp] = ((unsigned)r.vc1.z << 16) | r.va1.z;
    *(unsigned int*)&sVT[vdg + 32 + 3][vkp] = ((unsigned)r.vc1.w << 16) | r.va1.w;
}

__device__ __forceinline__ bf16x8 pack_pa(const f32x16& p, int i0)
{
    unsigned a0, a1, a2, a3;
    asm("v_cvt_pk_bf16_f32 %0, %1, %2" : "=v"(a0) : "v"(p[i0 + 0]), "v"(p[i0 + 1]));
    asm("v_cvt_pk_bf16_f32 %0, %1, %2" : "=v"(a1) : "v"(p[i0 + 2]), "v"(p[i0 + 3]));
    asm("v_cvt_pk_bf16_f32 %0, %1, %2" : "=v"(a2) : "v"(p[i0 + 4]), "v"(p[i0 + 5]));
    asm("v_cvt_pk_bf16_f32 %0, %1, %2" : "=v"(a3) : "v"(p[i0 + 6]), "v"(p[i0 + 7]));
    const u32x2 s02 = __builtin_amdgcn_permlane32_swap(a0, a2, false, false);
    const u32x2 s13 = __builtin_amdgcn_permlane32_swap(a1, a3, false, false);
    return __builtin_bit_cast(bf16x8, (u32x4){s02[0], s13[0], s02[1], s13[1]});
}

// One q-set's QK dual-chain -> softmax -> pack.
__device__ __forceinline__ void qk_sm_pack(
    const bf16x8* aK, const bf16x8* bQ, bf16x8* pa, float& lsum)
{
    f32x16 p0, p1;
#pragma unroll
    for (int i = 0; i < 16; ++i) { p0[i] = 0.f; p1[i] = 0.f; }
    __builtin_amdgcn_s_setprio(1);
#pragma unroll
    for (int ks = 0; ks < 4; ++ks) {
        p0 = __builtin_amdgcn_mfma_f32_32x32x16_bf16(aK[ks * 2],     bQ[ks], p0, 0, 0, 0);
        p1 = __builtin_amdgcn_mfma_f32_32x32x16_bf16(aK[ks * 2 + 1], bQ[ks], p1, 0, 0, 0);
    }
    __builtin_amdgcn_s_setprio(0);
    float ps = 0.f;
#pragma unroll
    for (int i = 0; i < 16; ++i) {
        p0[i] = __builtin_amdgcn_exp2f(p0[i]);
        p1[i] = __builtin_amdgcn_exp2f(p1[i]);
        ps += p0[i] + p1[i];
    }
    lsum += ps;
    pa[0] = pack_pa(p0, 0);
    pa[1] = pack_pa(p0, 8);
    pa[2] = pack_pa(p1, 0);
    pa[3] = pack_pa(p1, 8);
}

__device__ __forceinline__ void attn_tile64(
    const __bf16 (*sK)[72], const __bf16 (*sVT)[72],
    const bf16x8* bQ0, const bf16x8* bQ1, int lq, int hi,
    f32x16& O00, f32x16& O01, f32x16& O10, f32x16& O11,
    float& ls0, float& ls1)
{
    // --- K fragments: read ONCE, serve both q-sets
    bf16x8 aK[8];
#pragma unroll
    for (int ks = 0; ks < 4; ++ks) {
        aK[ks * 2]     = *(const bf16x8*)&sK[lq][ks * 16 + hi * 8];
        aK[ks * 2 + 1] = *(const bf16x8*)&sK[32 + lq][ks * 16 + hi * 8];
    }

    bf16x8 pa[4];
    qk_sm_pack(aK, bQ0, pa, ls0);

    // --- V fragments: read ONCE (latency hidden under sm0), serve both q-sets
    bf16x8 vbf[8];
#pragma unroll
    for (int ks = 0; ks < 4; ++ks) {
        vbf[ks * 2]     = *(const bf16x8*)&sVT[lq][ks * 16 + hi * 8];
        vbf[ks * 2 + 1] = *(const bf16x8*)&sVT[32 + lq][ks * 16 + hi * 8];
    }

    __builtin_amdgcn_s_setprio(1);
#pragma unroll
    for (int ks = 0; ks < 4; ++ks) {
        O00 = __builtin_amdgcn_mfma_f32_32x32x16_bf16(pa[ks], vbf[ks * 2],     O00, 0, 0, 0);
        O01 = __builtin_amdgcn_mfma_f32_32x32x16_bf16(pa[ks], vbf[ks * 2 + 1], O01, 0, 0, 0);
    }
    __builtin_amdgcn_s_setprio(0);

    qk_sm_pack(aK, bQ1, pa, ls1);

    __builtin_amdgcn_s_setprio(1);
#pragma unroll
    for (int ks = 0; ks < 4; ++ks) {
        O10 = __builtin_amdgcn_mfma_f32_32x32x16_bf16(pa[ks], vbf[ks * 2],     O10, 0, 0, 0);
        O11 = __builtin_amdgcn_mfma_f32_32x32x16_bf16(pa[ks], vbf[ks * 2 + 1], O11, 0, 0, 0);
    }
    __builtin_amdgcn_s_setprio(0);
}

__global__ __launch_bounds__(256, 2) void attn_kernel(
    const __bf16* __restrict__ qw, const __bf16* __restrict__ kw,
    const __bf16* __restrict__ vw, __bf16* __restrict__ ow)
{
    __shared__ __bf16 sK0[64][72], sVT0[64][72];
    __shared__ __bf16 sK1[64][72], sVT1[64][72];

    const int t    = threadIdx.x;
    const int lane = t & 63;
    const int w    = t >> 6;
    const int lq   = lane & 31;
    const int hi   = lane >> 5;

    const int bh  = blockIdx.y;
    const int b   = bh >> 5;
    const int h   = bh & 31;
    const int kvh = h >> 2;
    const int q0  = blockIdx.x * 256 + w * 64;   // this wave's 64 q-rows

    bf16x8 bQ0[4], bQ1[4];
    {
        const __bf16* qr0 = qw + (((size_t)b * S_ + q0 + lq) * H_ + h) * D_;
        const __bf16* qr1 = qw + (((size_t)b * S_ + q0 + 32 + lq) * H_ + h) * D_;
#pragma unroll
        for (int ks = 0; ks < 4; ++ks) {
            bQ0[ks] = *(const bf16x8*)(qr0 + ks * 16 + hi * 8);
            bQ1[ks] = *(const bf16x8*)(qr1 + ks * 16 + hi * 8);
        }
    }

    f32x16 O00, O01, O10, O11;
#pragma unroll
    for (int i = 0; i < 16; ++i) { O00[i] = 0.f; O01[i] = 0.f; O10[i] = 0.f; O11[i] = 0.f; }
    float ls0 = 0.f, ls1 = 0.f;

    const __bf16* kbase = kw + ((size_t)b * S_ * HKV_ + kvh) * D_;
    const __bf16* vbase = vw + ((size_t)b * S_ * HKV_ + kvh) * D_;
    const int kkey = t >> 2,        kd  = (t & 3) * 16;
    const int vkp  = (t & 31) * 2,  vdg = (t >> 5) * 4;

    StageRegs sr;
    stage_load(sr, kbase, vbase, 0, kkey, kd, vkp, vdg);
    stage_write(sr, sK0, sVT0, kkey, kd, vkp, vdg);
    __syncthreads();

#pragma unroll 1
    for (int j0 = 0; j0 < S_; j0 += 128) {
        StageRegs nx;
        stage_load(nx, kbase, vbase, j0 + 64, kkey, kd, vkp, vdg);
        attn_tile64(sK0, sVT0, bQ0, bQ1, lq, hi, O00, O01, O10, O11, ls0, ls1);
        stage_write(nx, sK1, sVT1, kkey, kd, vkp, vdg);
        __syncthreads();
        if (j0 + 128 < S_)
            stage_load(nx, kbase, vbase, j0 + 128, kkey, kd, vkp, vdg);
        attn_tile64(sK1, sVT1, bQ0, bQ1, lq, hi, O00, O01, O10, O11, ls0, ls1);
        if (j0 + 128 < S_)
            stage_write(nx, sK0, sVT0, kkey, kd, vkp, vdg);
        __syncthreads();
    }

    // lane and lane^32 hold complementary key-halves of each denominator.
    ls0 += __shfl_xor(ls0, 32);
    ls1 += __shfl_xor(ls1, 32);
    const float inv0 = 1.0f / ls0;
    const float inv1 = 1.0f / ls1;

    // O C-layout: col = lane&31 = d-in-block, row q = (r&3)+8*(r>>2)+4*hi.
#pragma unroll
    for (int r = 0; r < 16; ++r) {
        const int qr = (r & 3) + 8 * (r >> 2) + 4 * hi;
        {
            const float li = __shfl(inv0, qr);
            __bf16* orow = ow + (((size_t)b * S_ + q0 + qr) * H_ + h) * D_;
            orow[lq]      = (__bf16)(O00[r] * li);
            orow[32 + lq] = (__bf16)(O01[r] * li);
        }
        {
            const float li = __shfl(inv1, qr);
            __bf16* orow = ow + (((size_t)b * S_ + q0 + 32 + qr) * H_ + h) * D_;
            orow[lq]      = (__bf16)(O10[r] * li);
            orow[32 + lq] = (__bf16)(O11[r] * li);
        }
    }
}

// ---------------------------------------------------------------------------
extern "C" void kernel_launch(void* const* d_in, const int* in_sizes, int n_in,
                              void* d_out, int out_size, void* d_ws, size_t ws_size,
                              hipStream_t stream)
{
    const float* x  = (const float*)d_in[0];
    const float* fc = (const float*)d_in[2];
    const float* fs = (const float*)d_in[3];
    const float* wq = (const float*)d_in[4];
    const float* wk = (const float*)d_in[5];
    const float* wv = (const float*)d_in[6];
    const float* wo = (const float*)d_in[7];
    const float* obias = (const float*)d_in[8];
    float* out = (float*)d_out;

    __bf16* ws  = (__bf16*)d_ws;
    __bf16* xb  = ws;                                    // 4096*2048
    __bf16* wT  = xb  + (size_t)4096 * 2048;             // 3072*2048 [wq^T|wk^T|wv^T]
    __bf16* woT = wT  + (size_t)3072 * 2048;             // 2048*2048
    __bf16* qb  = woT + (size_t)2048 * 2048;             // B,S,H,D
    __bf16* kb  = qb  + (size_t)B_ * S_ * H_ * D_;       // B,S,HKV,D
    __bf16* vb  = kb  + (size_t)B_ * S_ * HKV_ * D_;
    __bf16* obf = vb  + (size_t)B_ * S_ * HKV_ * D_;     // B,S,H,D

    convert_kernel<<<4096, 256, 0, stream>>>(x, xb, 4096 * 2048 / 8);
    transpose_convert_all_kernel<<<dim3(160, 64), 256, 0, stream>>>(
        wq, wk, wv, wo, wT, woT);

    gemm_qkv_kernel<<<192, 512, 0, stream>>>(xb, wT, fc, fs, qb, kb, vb);

    attn_kernel<<<dim3(S_ / 256, B_ * H_), 256, 0, stream>>>(qb, kb, vb, obf);

    gemm_out_kernel<<<256, 512, 0, stream>>>(obf, woT, obias, out);
}